// Round 3
// baseline (68.301 us; speedup 1.0000x reference)
//
#include <hip/hip_runtime.h>

// 3x3 median filter, zero padding, B=128, C=1, H=W=512, fp32.
// Each thread produces 8 horizontally-consecutive output pixels.
// Median-of-9 via shared sorted columns + v_min3/med3/max3 single instrs:
//   per column (3 vertical elems): lo=min3, mi=med3, hi=max3   (3 instrs)
//   per output (3 sorted columns): med3(max3(lo), med3(mi), min3(hi)) (4 instrs)
// All ops are exact-select -> bitwise-identical to sort-based median.

typedef float f32x4 __attribute__((ext_vector_type(4)));

__device__ __forceinline__ float med3(float a, float b, float c) {
    return __builtin_amdgcn_fmed3f(a, b, c);
}
__device__ __forceinline__ float min3(float a, float b, float c) {
    return fminf(fminf(a, b), c);   // fuses to v_min3_f32
}
__device__ __forceinline__ float max3(float a, float b, float c) {
    return fmaxf(fmaxf(a, b), c);   // fuses to v_max3_f32
}

__global__ __launch_bounds__(256) void median3x3_kernel(
        const float* __restrict__ in, float* __restrict__ out) {
    const int W = 512, H = 512;
    int tid = blockIdx.x * 256 + threadIdx.x;

    int x8   = tid & 63;         // 64 8-px chunks per row; one wave == one row
    int rest = tid >> 6;
    int y    = rest & 511;
    int bi   = rest >> 9;        // batch index 0..127
    int x0   = x8 << 3;          // leading column of this thread's 8 pixels

    const float* base = in + (size_t)bi * H * W;

    // v[row][col], col 0 == x0-1 .. col 9 == x0+8, zero-padded out of bounds.
    float v[3][10];
#pragma unroll
    for (int dy = 0; dy < 3; ++dy) {
        int yy = y + dy - 1;
        if (yy >= 0 && yy < H) {                 // wave-uniform branch
            const float* rp = base + (size_t)yy * W + x0;
            f32x4 m0 = *reinterpret_cast<const f32x4*>(rp);
            f32x4 m1 = *reinterpret_cast<const f32x4*>(rp + 4);
            v[dy][1] = m0.x; v[dy][2] = m0.y; v[dy][3] = m0.z; v[dy][4] = m0.w;
            v[dy][5] = m1.x; v[dy][6] = m1.y; v[dy][7] = m1.z; v[dy][8] = m1.w;
            v[dy][0] = (x0 > 0)     ? rp[-1] : 0.0f;   // diverges only at lane 0
            v[dy][9] = (x0 + 8 < W) ? rp[8]  : 0.0f;   // diverges only at lane 63
        } else {
#pragma unroll
            for (int c = 0; c < 10; ++c) v[dy][c] = 0.0f;
        }
    }

    // Sort each vertical column of 3.
    float lo[10], mi[10], hi[10];
#pragma unroll
    for (int c = 0; c < 10; ++c) {
        lo[c] = min3(v[0][c], v[1][c], v[2][c]);
        mi[c] = med3(v[0][c], v[1][c], v[2][c]);
        hi[c] = max3(v[0][c], v[1][c], v[2][c]);
    }

    // Median of 9 from 3 sorted columns, sliding window.
    float o[8];
#pragma unroll
    for (int j = 0; j < 8; ++j) {
        float a = max3(lo[j], lo[j + 1], lo[j + 2]);
        float b = med3(mi[j], mi[j + 1], mi[j + 2]);
        float c = min3(hi[j], hi[j + 1], hi[j + 2]);
        o[j] = med3(a, b, c);
    }

    float* op = out + ((size_t)bi * H + y) * W + x0;
    f32x4 s0 = { o[0], o[1], o[2], o[3] };
    f32x4 s1 = { o[4], o[5], o[6], o[7] };
    __builtin_nontemporal_store(s0, reinterpret_cast<f32x4*>(op));
    __builtin_nontemporal_store(s1, reinterpret_cast<f32x4*>(op + 4));
}

extern "C" void kernel_launch(void* const* d_in, const int* in_sizes, int n_in,
                              void* d_out, int out_size, void* d_ws, size_t ws_size,
                              hipStream_t stream) {
    const float* x = (const float*)d_in[0];
    float* out = (float*)d_out;

    const int B = 128, H = 512, W = 512;
    int total_threads = B * H * (W / 8);          // 4,194,304
    int blocks = total_threads / 256;             // 16,384

    median3x3_kernel<<<blocks, 256, 0, stream>>>(x, out);
}

// Round 4
// 48.143 us; speedup vs baseline: 1.4187x; 1.4187x over previous
//
#include <hip/hip_runtime.h>

// 3x3 median filter, zero padding, B=128, C=1, H=W=512, fp32.
// Each thread: 2 output rows x 8 px, as two 4-px windows (cols 4*lane and
// 256+4*lane) so every load/store instruction is a contiguous 1KiB wave
// segment. 4 input rows are loaded once into registers and reused for both
// output rows. Horizontal halo columns come from cross-lane shuffles (no
// scalar loads). Median-of-9 = sorted-column trick with single-instruction
// v_min3/v_med3/v_max3; all ops exact-select -> absmax stays 0.

typedef float f32x4 __attribute__((ext_vector_type(4)));

__device__ __forceinline__ float med3(float a, float b, float c) {
    return __builtin_amdgcn_fmed3f(a, b, c);
}
__device__ __forceinline__ float min3(float a, float b, float c) {
    return fminf(fminf(a, b), c);   // fuses to v_min3_f32
}
__device__ __forceinline__ float max3(float a, float b, float c) {
    return fmaxf(fmaxf(a, b), c);   // fuses to v_max3_f32
}

__global__ __launch_bounds__(256) void median3x3_kernel(
        const float* __restrict__ in, float* __restrict__ out) {
    const int W = 512, H = 512;
    int lane = threadIdx.x & 63;
    int gw   = blockIdx.x * 4 + (threadIdx.x >> 6);  // global wave id
    int yt   = gw & 255;                             // row-pair within image
    int bi   = gw >> 8;                              // image index 0..127
    int y0   = yt << 1;                              // first output row

    const float* base = in + (size_t)bi * H * W;

    // Input rows y0-1 .. y0+2. A = cols [4l,4l+4), B = cols [256+4l,256+4l+4).
    float A[4][4], B[4][4];
    float AL[4], AR[4], BL[4], BR[4];   // halo cols 4l-1, 4l+4, 256+4l-1, 256+4l+4

#pragma unroll
    for (int k = 0; k < 4; ++k) {
        int yy = y0 - 1 + k;
        if (yy >= 0 && yy < H) {                     // wave-uniform branch
            const float* rp = base + (size_t)yy * W;
            f32x4 va = *reinterpret_cast<const f32x4*>(rp + lane * 4);
            f32x4 vb = *reinterpret_cast<const f32x4*>(rp + 256 + lane * 4);
            A[k][0] = va.x; A[k][1] = va.y; A[k][2] = va.z; A[k][3] = va.w;
            B[k][0] = vb.x; B[k][1] = vb.y; B[k][2] = vb.z; B[k][3] = vb.w;
        } else {
#pragma unroll
            for (int c = 0; c < 4; ++c) { A[k][c] = 0.0f; B[k][c] = 0.0f; }
        }
    }

#pragma unroll
    for (int k = 0; k < 4; ++k) {
        float al    = __shfl_up  (A[k][3], 1, 64);   // lane-1's A3 == col 4l-1
        float ar    = __shfl_down(A[k][0], 1, 64);   // lane+1's A0 == col 4l+4
        float bl    = __shfl_up  (B[k][3], 1, 64);
        float br    = __shfl_down(B[k][0], 1, 64);
        float seamR = __shfl     (B[k][0], 0, 64);   // col 256 (lane 0's B0)
        float seamL = __shfl     (A[k][3], 63, 64);  // col 255 (lane 63's A3)
        AL[k] = (lane == 0)  ? 0.0f  : al;           // image left edge pad
        AR[k] = (lane == 63) ? seamR : ar;           // seam at col 255/256
        BL[k] = (lane == 0)  ? seamL : bl;
        BR[k] = (lane == 63) ? 0.0f  : br;           // image right edge pad
    }

    float* obase = out + ((size_t)bi * H + y0) * W;

#pragma unroll
    for (int r = 0; r < 2; ++r) {        // output rows y0+r, input rows r..r+2
        float lo[6], mi[6], hi[6];

        // window A: columns 4l-1 .. 4l+4
#pragma unroll
        for (int c = 0; c < 6; ++c) {
            float x0 = (c == 0) ? AL[r]     : (c == 5) ? AR[r]     : A[r][c - 1];
            float x1 = (c == 0) ? AL[r + 1] : (c == 5) ? AR[r + 1] : A[r + 1][c - 1];
            float x2 = (c == 0) ? AL[r + 2] : (c == 5) ? AR[r + 2] : A[r + 2][c - 1];
            lo[c] = min3(x0, x1, x2);
            mi[c] = med3(x0, x1, x2);
            hi[c] = max3(x0, x1, x2);
        }
        f32x4 oa;
        oa.x = med3(max3(lo[0], lo[1], lo[2]), med3(mi[0], mi[1], mi[2]), min3(hi[0], hi[1], hi[2]));
        oa.y = med3(max3(lo[1], lo[2], lo[3]), med3(mi[1], mi[2], mi[3]), min3(hi[1], hi[2], hi[3]));
        oa.z = med3(max3(lo[2], lo[3], lo[4]), med3(mi[2], mi[3], mi[4]), min3(hi[2], hi[3], hi[4]));
        oa.w = med3(max3(lo[3], lo[4], lo[5]), med3(mi[3], mi[4], mi[5]), min3(hi[3], hi[4], hi[5]));

        // window B: columns 256+4l-1 .. 256+4l+4
#pragma unroll
        for (int c = 0; c < 6; ++c) {
            float x0 = (c == 0) ? BL[r]     : (c == 5) ? BR[r]     : B[r][c - 1];
            float x1 = (c == 0) ? BL[r + 1] : (c == 5) ? BR[r + 1] : B[r + 1][c - 1];
            float x2 = (c == 0) ? BL[r + 2] : (c == 5) ? BR[r + 2] : B[r + 2][c - 1];
            lo[c] = min3(x0, x1, x2);
            mi[c] = med3(x0, x1, x2);
            hi[c] = max3(x0, x1, x2);
        }
        f32x4 ob;
        ob.x = med3(max3(lo[0], lo[1], lo[2]), med3(mi[0], mi[1], mi[2]), min3(hi[0], hi[1], hi[2]));
        ob.y = med3(max3(lo[1], lo[2], lo[3]), med3(mi[1], mi[2], mi[3]), min3(hi[1], hi[2], hi[3]));
        ob.z = med3(max3(lo[2], lo[3], lo[4]), med3(mi[2], mi[3], mi[4]), min3(hi[2], hi[3], hi[4]));
        ob.w = med3(max3(lo[3], lo[4], lo[5]), med3(mi[3], mi[4], mi[5]), min3(hi[3], hi[4], hi[5]));

        float* op = obase + (size_t)r * W;
        *reinterpret_cast<f32x4*>(op + lane * 4)       = oa;
        *reinterpret_cast<f32x4*>(op + 256 + lane * 4) = ob;
    }
}

extern "C" void kernel_launch(void* const* d_in, const int* in_sizes, int n_in,
                              void* d_out, int out_size, void* d_ws, size_t ws_size,
                              hipStream_t stream) {
    const float* x = (const float*)d_in[0];
    float* out = (float*)d_out;

    // 128 images x 256 row-pairs = 32768 waves = 8192 blocks of 4 waves.
    int blocks = 8192;
    median3x3_kernel<<<blocks, 256, 0, stream>>>(x, out);
}

// Round 5
// 41.866 us; speedup vs baseline: 1.6314x; 1.1499x over previous
//
#include <hip/hip_runtime.h>

// 3x3 median filter, zero padding, B=128, C=1, H=W=512, fp32.
// Each thread: 2 output rows x 8 px, as two 4-px windows (cols 4*lane and
// 256+4*lane) so every load/store instruction is a contiguous 1KiB wave
// segment. 4 input rows load once into registers, reused for both output
// rows. Horizontal halos via cross-lane shuffles. Median-of-9 = sorted-column
// trick with v_min3/v_med3/v_max3 (exact-select -> absmax 0).
// R4: nontemporal coalesced stores (full 64B lines -> no amplification,
// keeps write stream out of L2/L3) + XCD-chunked block swizzle (each XCD
// owns 16 whole images -> halo-row reuse becomes same-XCD L2 hits).

typedef float f32x4 __attribute__((ext_vector_type(4)));

__device__ __forceinline__ float med3(float a, float b, float c) {
    return __builtin_amdgcn_fmed3f(a, b, c);
}
__device__ __forceinline__ float min3(float a, float b, float c) {
    return fminf(fminf(a, b), c);   // fuses to v_min3_f32
}
__device__ __forceinline__ float max3(float a, float b, float c) {
    return fmaxf(fmaxf(a, b), c);   // fuses to v_max3_f32
}

__global__ __launch_bounds__(256) void median3x3_kernel(
        const float* __restrict__ in, float* __restrict__ out) {
    const int W = 512, H = 512;
    int lane = threadIdx.x & 63;

    // XCD-chunked swizzle: 8192 blocks, 8 XCDs, round-robin dispatch ->
    // XCD x gets swizzled ids [x*1024, (x+1)*1024) = 16 contiguous images.
    int bid = blockIdx.x;
    int swz = (bid & 7) * 1024 + (bid >> 3);

    int gw   = swz * 4 + (threadIdx.x >> 6);         // global wave id
    int yt   = gw & 255;                             // row-pair within image
    int bi   = gw >> 8;                              // image index 0..127
    int y0   = yt << 1;                              // first output row

    const float* base = in + (size_t)bi * H * W;

    // Input rows y0-1 .. y0+2. A = cols [4l,4l+4), B = cols [256+4l,256+4l+4).
    float A[4][4], B[4][4];
    float AL[4], AR[4], BL[4], BR[4];   // halo cols 4l-1, 4l+4, 256+4l-1, 256+4l+4

#pragma unroll
    for (int k = 0; k < 4; ++k) {
        int yy = y0 - 1 + k;
        if (yy >= 0 && yy < H) {                     // wave-uniform branch
            const float* rp = base + (size_t)yy * W;
            f32x4 va = *reinterpret_cast<const f32x4*>(rp + lane * 4);
            f32x4 vb = *reinterpret_cast<const f32x4*>(rp + 256 + lane * 4);
            A[k][0] = va.x; A[k][1] = va.y; A[k][2] = va.z; A[k][3] = va.w;
            B[k][0] = vb.x; B[k][1] = vb.y; B[k][2] = vb.z; B[k][3] = vb.w;
        } else {
#pragma unroll
            for (int c = 0; c < 4; ++c) { A[k][c] = 0.0f; B[k][c] = 0.0f; }
        }
    }

#pragma unroll
    for (int k = 0; k < 4; ++k) {
        float al    = __shfl_up  (A[k][3], 1, 64);   // lane-1's A3 == col 4l-1
        float ar    = __shfl_down(A[k][0], 1, 64);   // lane+1's A0 == col 4l+4
        float bl    = __shfl_up  (B[k][3], 1, 64);
        float br    = __shfl_down(B[k][0], 1, 64);
        float seamR = __shfl     (B[k][0], 0, 64);   // col 256 (lane 0's B0)
        float seamL = __shfl     (A[k][3], 63, 64);  // col 255 (lane 63's A3)
        AL[k] = (lane == 0)  ? 0.0f  : al;           // image left edge pad
        AR[k] = (lane == 63) ? seamR : ar;           // seam at col 255/256
        BL[k] = (lane == 0)  ? seamL : bl;
        BR[k] = (lane == 63) ? 0.0f  : br;           // image right edge pad
    }

    float* obase = out + ((size_t)bi * H + y0) * W;

#pragma unroll
    for (int r = 0; r < 2; ++r) {        // output rows y0+r, input rows r..r+2
        float lo[6], mi[6], hi[6];

        // window A: columns 4l-1 .. 4l+4
#pragma unroll
        for (int c = 0; c < 6; ++c) {
            float x0 = (c == 0) ? AL[r]     : (c == 5) ? AR[r]     : A[r][c - 1];
            float x1 = (c == 0) ? AL[r + 1] : (c == 5) ? AR[r + 1] : A[r + 1][c - 1];
            float x2 = (c == 0) ? AL[r + 2] : (c == 5) ? AR[r + 2] : A[r + 2][c - 1];
            lo[c] = min3(x0, x1, x2);
            mi[c] = med3(x0, x1, x2);
            hi[c] = max3(x0, x1, x2);
        }
        f32x4 oa;
        oa.x = med3(max3(lo[0], lo[1], lo[2]), med3(mi[0], mi[1], mi[2]), min3(hi[0], hi[1], hi[2]));
        oa.y = med3(max3(lo[1], lo[2], lo[3]), med3(mi[1], mi[2], mi[3]), min3(hi[1], hi[2], hi[3]));
        oa.z = med3(max3(lo[2], lo[3], lo[4]), med3(mi[2], mi[3], mi[4]), min3(hi[2], hi[3], hi[4]));
        oa.w = med3(max3(lo[3], lo[4], lo[5]), med3(mi[3], mi[4], mi[5]), min3(hi[3], hi[4], hi[5]));

        // window B: columns 256+4l-1 .. 256+4l+4
#pragma unroll
        for (int c = 0; c < 6; ++c) {
            float x0 = (c == 0) ? BL[r]     : (c == 5) ? BR[r]     : B[r][c - 1];
            float x1 = (c == 0) ? BL[r + 1] : (c == 5) ? BR[r + 1] : B[r + 1][c - 1];
            float x2 = (c == 0) ? BL[r + 2] : (c == 5) ? BR[r + 2] : B[r + 2][c - 1];
            lo[c] = min3(x0, x1, x2);
            mi[c] = med3(x0, x1, x2);
            hi[c] = max3(x0, x1, x2);
        }
        f32x4 ob;
        ob.x = med3(max3(lo[0], lo[1], lo[2]), med3(mi[0], mi[1], mi[2]), min3(hi[0], hi[1], hi[2]));
        ob.y = med3(max3(lo[1], lo[2], lo[3]), med3(mi[1], mi[2], mi[3]), min3(hi[1], hi[2], hi[3]));
        ob.z = med3(max3(lo[2], lo[3], lo[4]), med3(mi[2], mi[3], mi[4]), min3(hi[2], hi[3], hi[4]));
        ob.w = med3(max3(lo[3], lo[4], lo[5]), med3(mi[3], mi[4], mi[5]), min3(hi[3], hi[4], hi[5]));

        float* op = obase + (size_t)r * W;
        __builtin_nontemporal_store(oa, reinterpret_cast<f32x4*>(op + lane * 4));
        __builtin_nontemporal_store(ob, reinterpret_cast<f32x4*>(op + 256 + lane * 4));
    }
}

extern "C" void kernel_launch(void* const* d_in, const int* in_sizes, int n_in,
                              void* d_out, int out_size, void* d_ws, size_t ws_size,
                              hipStream_t stream) {
    const float* x = (const float*)d_in[0];
    float* out = (float*)d_out;

    // 128 images x 256 row-pairs = 32768 waves = 8192 blocks of 4 waves.
    int blocks = 8192;
    median3x3_kernel<<<blocks, 256, 0, stream>>>(x, out);
}